// Round 7
// baseline (800.743 us; speedup 1.0000x reference)
//
#include <hip/hip_runtime.h>

#define BB 64
#define TT 1024
#define CC 2
#define NN 128
#define CHW 8            // chains per workgroup = waves per workgroup (512 thr)

#define REP16(M) M(0)M(1)M(2)M(3)M(4)M(5)M(6)M(7)M(8)M(9)M(10)M(11)M(12)M(13)M(14)M(15)

// fp32 -> bf16 bits, round-to-nearest-even (inputs are never NaN here)
static __device__ __forceinline__ unsigned f2bf(float x) {
    const unsigned u = __float_as_uint(x);
    return (u + 0x7FFFu + ((u >> 16) & 1u)) >> 16;
}
static __device__ __forceinline__ unsigned pk2(float lo, float hi) {
    return f2bf(lo) | (f2bf(hi) << 16);
}
static __device__ __forceinline__ float bcast0(float x) {
    return __int_as_float(__builtin_amdgcn_readfirstlane(__float_as_int(x)));
}

// D.f32 += S0.bf16[0]*S1.bf16[0] + S0.bf16[1]*S1.bf16[1]  (VOP3P, VGPR srcs)
#define DOT(acc, pp, ee) \
    asm("v_dot2_f32_bf16 %0, %1, %2, %0" : "+v"(acc) : "v"(pp), "v"(ee));

// ROUND-7: STRUCTURE, not storage. R6 proved E residency (VGPR=72 = 64 E + 8)
// with dur unchanged at ~480 — the per-step cost is structural: 2-wave
// cross-SIMD barrier + LDS round-trip + dep chain, fully latency-exposed at
// 1 wave/SIMD (and likely a throttled clock at 2% occupancy). New shape:
//   - 1 wave per (b,c) chain, 64 lanes, lane l owns tags 2l and 2l+1.
//     NO barrier: same-wave LDS exchange relies on in-order DS pipe
//     (whole-wave instr granularity); shift broadcast via readfirstlane.
//   - 8 chains per 512-thread workgroup -> 8 independent waves per CU =
//     2 waves/SIMD: one chain's dots issue while the other's LDS round-trip
//     is in flight (first actual TLP of the session).
// E: both tag columns (128 packed words) as plain C values; waves_per_eu(2,2)
// sets the allocator budget to 256. Overflow spills to AGPR restores which
// hide under structure (R6 lesson).
#define E_INIT(c) \
    const unsigned uA##c##_0 = pk2(__expf(tr[(8*(c)+0)*NN + jA]), __expf(tr[(8*(c)+1)*NN + jA])); \
    const unsigned uA##c##_1 = pk2(__expf(tr[(8*(c)+2)*NN + jA]), __expf(tr[(8*(c)+3)*NN + jA])); \
    const unsigned uA##c##_2 = pk2(__expf(tr[(8*(c)+4)*NN + jA]), __expf(tr[(8*(c)+5)*NN + jA])); \
    const unsigned uA##c##_3 = pk2(__expf(tr[(8*(c)+6)*NN + jA]), __expf(tr[(8*(c)+7)*NN + jA])); \
    const unsigned uB##c##_0 = pk2(__expf(tr[(8*(c)+0)*NN + jB]), __expf(tr[(8*(c)+1)*NN + jB])); \
    const unsigned uB##c##_1 = pk2(__expf(tr[(8*(c)+2)*NN + jB]), __expf(tr[(8*(c)+3)*NN + jB])); \
    const unsigned uB##c##_2 = pk2(__expf(tr[(8*(c)+4)*NN + jB]), __expf(tr[(8*(c)+5)*NN + jB])); \
    const unsigned uB##c##_3 = pk2(__expf(tr[(8*(c)+6)*NN + jB]), __expf(tr[(8*(c)+7)*NN + jB]));

// Per chunk c: one b128 broadcast read (p pairs k=8c..8c+7) + 8 dot2
// (4 for tag A = 2l, 4 for tag B = 2l+1).
#define MV(c) { const uint4 q = pb[c]; \
    DOT(xA0, q.x, uA##c##_0) DOT(xA1, q.y, uA##c##_1) \
    DOT(xA2, q.z, uA##c##_2) DOT(xA3, q.w, uA##c##_3) \
    DOT(xB0, q.x, uB##c##_0) DOT(xB1, q.y, uB##c##_1) \
    DOT(xB2, q.z, uB##c##_2) DOT(xB3, q.w, uB##c##_3) }

// Critical-path factoring (kept): alpha_t = S_t + log(s_t) + e_t,
//   p_{t+1} = exp(alpha_t - S_{t+1}) = s_t * exp(S_t + e_t - S_{t+1})
// S carried in SGPRs via readfirstlane (tag 0 lives in lane 0), one full
// iteration of slack on the log.
__global__ __launch_bounds__(CHW * 64, 1) __attribute__((amdgpu_waves_per_eu(2, 2)))
void crf_logz_kernel(const float* __restrict__ emissions,
                     const int* __restrict__ lengths,
                     const float* __restrict__ transitions,
                     const float* __restrict__ start_trans,
                     const float* __restrict__ end_trans,
                     float* __restrict__ out)
{
    const int w  = threadIdx.x >> 6;          // wave id = chain slot
    const int l  = threadIdx.x & 63;          // lane, owns tags 2l, 2l+1
    const int chain = blockIdx.x * CHW + w;   // = b*CC + c
    const int b  = chain >> 1;
    const int c  = chain & 1;
    const int jA = 2 * l, jB = 2 * l + 1;

    __shared__ __align__(16) unsigned pbufs[CHW][2][64];  // per-wave p words, dbuf

    const float* tr = transitions + c * NN * NN;
    REP16(E_INIT)                          // 128 packed words = both E columns

    const int len  = lengths[b];           // in [T/2, T]
    const int tmax = len - 1;

    // emissions[b][t][c][*] as float2: lane l -> tags 2l,2l+1 (coalesced 8B/lane)
    const float2* em2 = (const float2*)(emissions + ((size_t)b * TT * CC + c) * NN);
    const int st = CC * NN / 2;            // float2 stride per t

    const float2 ez = em2[l];              // t = 0
    const float a0A = start_trans[c * NN + jA] + ez.x;
    const float a0B = start_trans[c * NN + jB] + ez.y;

    float Scur = 0.f;                      // S_1 = 0 (|alpha_0| < ~12)
    float Snxt = bcast0(a0A);              // S_2 = alpha_0[0]

    unsigned pbits = pk2(__expf(a0A), __expf(a0B));   // p_1 for both tags

    // 3-deep register emission pipeline (never drained: no barrier exists)
    const int t1 = (1 < tmax) ? 1 : tmax;
    const int t2 = (2 < tmax) ? 2 : tmax;
    const int t3 = (3 < tmax) ? 3 : tmax;
    float2 ec  = em2[(size_t)t1 * st + l];  // e_t
    float2 e1  = em2[(size_t)t2 * st + l];  // e_{t+1}
    float2 e2v = em2[(size_t)t3 * st + l];  // e_{t+2}

    float sA = 0.f, sB = 0.f, Sfin = 0.f;
    float2 efin = ec;

    for (int t = 1; t < len; ++t) {
        pbufs[w][t & 1][l] = pbits;        // p_t word l = (p[2l], p[2l+1])
        asm volatile("" ::: "memory");     // no compiler reorder; DS pipe is
                                           // in-order per wave (whole-wave
                                           // write precedes the reads below)

        // prefetch emission for t+3 (clamped)
        const int tp = (t + 3 <= tmax) ? (t + 3) : tmax;
        const float2 el = em2[(size_t)tp * st + l];

        const float fA = __expf(Scur + ec.x - Snxt);  // off the dot chain
        const float fB = __expf(Scur + ec.y - Snxt);

        const uint4* __restrict__ pb = (const uint4*)pbufs[w][t & 1];
        float xA0 = 0.f, xA1 = 0.f, xA2 = 0.f, xA3 = 0.f;
        float xB0 = 0.f, xB1 = 0.f, xB2 = 0.f, xB3 = 0.f;
        REP16(MV)                          // 16 b128 broadcasts + 128 dot2
        sA = (xA0 + xA1) + (xA2 + xA3);
        sB = (xB0 + xB1) + (xB2 + xB3);

        // S_{t+2} = alpha_t[0]; log has a full iteration of slack
        const float Snew = bcast0(Scur + __logf(sA) + ec.x);

        pbits = pk2(sA * fA, sB * fB);     // p_{t+1} (critical: mul + pack)

        Sfin = Scur; efin = ec;            // snapshot for epilogue
        Scur = Snxt; Snxt = Snew;
        ec = e1; e1 = e2v; e2v = el;
    }

    // alpha_{len-1} for both tags
    float alphaA = (tmax == 0) ? a0A : (Sfin + __logf(sA) + efin.x);
    float alphaB = (tmax == 0) ? a0B : (Sfin + __logf(sB) + efin.y);
    alphaA += end_trans[c * NN + jA];
    alphaB += end_trans[c * NN + jB];

    // wave-internal logsumexp over 128 tags (no LDS, no barrier)
    float m = fmaxf(alphaA, alphaB);
    #pragma unroll
    for (int off = 32; off > 0; off >>= 1)
        m = fmaxf(m, __shfl_xor(m, off));
    float ss = __expf(alphaA - m) + __expf(alphaB - m);
    #pragma unroll
    for (int off = 32; off > 0; off >>= 1)
        ss += __shfl_xor(ss, off);
    if (l == 0) out[chain] = m + __logf(ss);
}

extern "C" void kernel_launch(void* const* d_in, const int* in_sizes, int n_in,
                              void* d_out, int out_size, void* d_ws, size_t ws_size,
                              hipStream_t stream) {
    const float* emissions   = (const float*)d_in[0];
    const int*   lengths     = (const int*)d_in[1];
    const float* transitions = (const float*)d_in[2];
    const float* start_t     = (const float*)d_in[3];
    const float* end_t       = (const float*)d_in[4];
    float* out = (float*)d_out;

    crf_logz_kernel<<<(BB * CC) / CHW, CHW * 64, 0, stream>>>(
        emissions, lengths, transitions, start_t, end_t, out);
}

// Round 8
// 640.185 us; speedup vs baseline: 1.2508x; 1.2508x over previous
//
#include <hip/hip_runtime.h>

#define BB 64
#define TT 1024
#define CC 2
#define NN 128
#define CHW 2            // chains (waves) per workgroup — DS-pipe sweet spot

#define REP16(M) M(0)M(1)M(2)M(3)M(4)M(5)M(6)M(7)M(8)M(9)M(10)M(11)M(12)M(13)M(14)M(15)

// fp32 -> bf16 bits, round-to-nearest-even (inputs are never NaN here)
static __device__ __forceinline__ unsigned f2bf(float x) {
    const unsigned u = __float_as_uint(x);
    return (u + 0x7FFFu + ((u >> 16) & 1u)) >> 16;
}
static __device__ __forceinline__ unsigned pk2(float lo, float hi) {
    return f2bf(lo) | (f2bf(hi) << 16);
}
static __device__ __forceinline__ float bcast0(float x) {
    return __int_as_float(__builtin_amdgcn_readfirstlane(__float_as_int(x)));
}

// D.f32 += S0.bf16[0]*S1.bf16[0] + S0.bf16[1]*S1.bf16[1]  (VOP3P, VGPR srcs)
#define DOT(acc, pp, ee) \
    asm("v_dot2_f32_bf16 %0, %1, %2, %0" : "+v"(acc) : "v"(pp), "v"(ee));

// ROUND-8: R7's barrier-free 1-wave-per-chain structure, de-oversubscribed.
// R7 (CHW=8) packed 8 waves/CU: per-CU DS load = 8x(16 b128 broadcasts + 1
// write) ~ 1536 cyc/step == measured 1700 — the LDS pipe was the serial
// resource. CHW=2: 64 CUs, 2 independent chains/CU on separate SIMDs ->
// per-CU DS ~ 384 cyc/step, and each wave's dot/exp phase overlaps the
// OTHER wave's DS round-trip (real TLP, no rendezvous). VGPR=84 in R7 also
// showed E re-spilled without amdgpu_num_vgpr (R6: attribute => resident);
// restored here (need ~150 live regs for 128 E words + pipeline).
#define E_INIT(c) \
    const unsigned uA##c##_0 = pk2(__expf(tr[(8*(c)+0)*NN + jA]), __expf(tr[(8*(c)+1)*NN + jA])); \
    const unsigned uA##c##_1 = pk2(__expf(tr[(8*(c)+2)*NN + jA]), __expf(tr[(8*(c)+3)*NN + jA])); \
    const unsigned uA##c##_2 = pk2(__expf(tr[(8*(c)+4)*NN + jA]), __expf(tr[(8*(c)+5)*NN + jA])); \
    const unsigned uA##c##_3 = pk2(__expf(tr[(8*(c)+6)*NN + jA]), __expf(tr[(8*(c)+7)*NN + jA])); \
    const unsigned uB##c##_0 = pk2(__expf(tr[(8*(c)+0)*NN + jB]), __expf(tr[(8*(c)+1)*NN + jB])); \
    const unsigned uB##c##_1 = pk2(__expf(tr[(8*(c)+2)*NN + jB]), __expf(tr[(8*(c)+3)*NN + jB])); \
    const unsigned uB##c##_2 = pk2(__expf(tr[(8*(c)+4)*NN + jB]), __expf(tr[(8*(c)+5)*NN + jB])); \
    const unsigned uB##c##_3 = pk2(__expf(tr[(8*(c)+6)*NN + jB]), __expf(tr[(8*(c)+7)*NN + jB]));

// Per chunk c: one b128 broadcast read (p pairs k=8c..8c+7) + 8 dot2
// (4 for tag A = 2l, 4 for tag B = 2l+1).
#define MV(c) { const uint4 q = pb[c]; \
    DOT(xA0, q.x, uA##c##_0) DOT(xA1, q.y, uA##c##_1) \
    DOT(xA2, q.z, uA##c##_2) DOT(xA3, q.w, uA##c##_3) \
    DOT(xB0, q.x, uB##c##_0) DOT(xB1, q.y, uB##c##_1) \
    DOT(xB2, q.z, uB##c##_2) DOT(xB3, q.w, uB##c##_3) }

// Critical-path factoring (kept): alpha_t = S_t + log(s_t) + e_t,
//   p_{t+1} = exp(alpha_t - S_{t+1}) = s_t * exp(S_t + e_t - S_{t+1})
// S carried via readfirstlane (tag 0 lives in lane 0); the log has a full
// iteration of slack; exp factors compute in parallel with the dots.
__global__ __launch_bounds__(CHW * 64, 1)
__attribute__((amdgpu_waves_per_eu(1, 1), amdgpu_num_vgpr(256)))
void crf_logz_kernel(const float* __restrict__ emissions,
                     const int* __restrict__ lengths,
                     const float* __restrict__ transitions,
                     const float* __restrict__ start_trans,
                     const float* __restrict__ end_trans,
                     float* __restrict__ out)
{
    const int w  = threadIdx.x >> 6;          // wave id = chain slot
    const int l  = threadIdx.x & 63;          // lane, owns tags 2l, 2l+1
    const int chain = blockIdx.x * CHW + w;   // = b*CC + c (both waves same b)
    const int b  = chain >> 1;
    const int c  = chain & 1;
    const int jA = 2 * l, jB = 2 * l + 1;

    __shared__ __align__(16) unsigned pbufs[CHW][2][64];  // per-wave p words, dbuf

    const float* tr = transitions + c * NN * NN;
    REP16(E_INIT)                          // 128 packed words = both E columns

    const int len  = lengths[b];           // in [T/2, T]
    const int tmax = len - 1;

    // emissions[b][t][c][*] as float2: lane l -> tags 2l,2l+1 (coalesced 8B/lane)
    const float2* em2 = (const float2*)(emissions + ((size_t)b * TT * CC + c) * NN);
    const int st = CC * NN / 2;            // float2 stride per t

    const float2 ez = em2[l];              // t = 0
    const float a0A = start_trans[c * NN + jA] + ez.x;
    const float a0B = start_trans[c * NN + jB] + ez.y;

    float Scur = 0.f;                      // S_1 = 0 (|alpha_0| < ~12)
    float Snxt = bcast0(a0A);              // S_2 = alpha_0[0]

    unsigned pbits = pk2(__expf(a0A), __expf(a0B));   // p_1 for both tags

    // 3-deep register emission pipeline (no barrier exists to drain it)
    const int t1 = (1 < tmax) ? 1 : tmax;
    const int t2 = (2 < tmax) ? 2 : tmax;
    const int t3 = (3 < tmax) ? 3 : tmax;
    float2 ec  = em2[(size_t)t1 * st + l];  // e_t
    float2 e1  = em2[(size_t)t2 * st + l];  // e_{t+1}
    float2 e2v = em2[(size_t)t3 * st + l];  // e_{t+2}

    float sA = 0.f, sB = 0.f, Sfin = 0.f;
    float2 efin = ec;

    for (int t = 1; t < len; ++t) {
        pbufs[w][t & 1][l] = pbits;        // p_t word l = (p[2l], p[2l+1])
        asm volatile("" ::: "memory");     // block compiler reorder; DS pipe is
                                           // in-order per wave (whole-wave
                                           // write precedes the reads below)

        // prefetch emission for t+3 (clamped)
        const int tp = (t + 3 <= tmax) ? (t + 3) : tmax;
        const float2 el = em2[(size_t)tp * st + l];

        const float fA = __expf(Scur + ec.x - Snxt);  // off the dot chain
        const float fB = __expf(Scur + ec.y - Snxt);

        const uint4* __restrict__ pb = (const uint4*)pbufs[w][t & 1];
        float xA0 = 0.f, xA1 = 0.f, xA2 = 0.f, xA3 = 0.f;
        float xB0 = 0.f, xB1 = 0.f, xB2 = 0.f, xB3 = 0.f;
        REP16(MV)                          // 16 b128 broadcasts + 128 dot2
        sA = (xA0 + xA1) + (xA2 + xA3);
        sB = (xB0 + xB1) + (xB2 + xB3);

        // S_{t+2} = alpha_t[0]; the log has a full iteration of slack
        const float Snew = bcast0(Scur + __logf(sA) + ec.x);

        pbits = pk2(sA * fA, sB * fB);     // p_{t+1} (critical: mul + pack)

        Sfin = Scur; efin = ec;            // snapshot for epilogue
        Scur = Snxt; Snxt = Snew;
        ec = e1; e1 = e2v; e2v = el;
    }

    // alpha_{len-1} for both tags
    float alphaA = (tmax == 0) ? a0A : (Sfin + __logf(sA) + efin.x);
    float alphaB = (tmax == 0) ? a0B : (Sfin + __logf(sB) + efin.y);
    alphaA += end_trans[c * NN + jA];
    alphaB += end_trans[c * NN + jB];

    // wave-internal logsumexp over 128 tags (no LDS, no barrier)
    float m = fmaxf(alphaA, alphaB);
    #pragma unroll
    for (int off = 32; off > 0; off >>= 1)
        m = fmaxf(m, __shfl_xor(m, off));
    float ss = __expf(alphaA - m) + __expf(alphaB - m);
    #pragma unroll
    for (int off = 32; off > 0; off >>= 1)
        ss += __shfl_xor(ss, off);
    if (l == 0) out[chain] = m + __logf(ss);
}

extern "C" void kernel_launch(void* const* d_in, const int* in_sizes, int n_in,
                              void* d_out, int out_size, void* d_ws, size_t ws_size,
                              hipStream_t stream) {
    const float* emissions   = (const float*)d_in[0];
    const int*   lengths     = (const int*)d_in[1];
    const float* transitions = (const float*)d_in[2];
    const float* start_t     = (const float*)d_in[3];
    const float* end_t       = (const float*)d_in[4];
    float* out = (float*)d_out;

    crf_logz_kernel<<<(BB * CC) / CHW, CHW * 64, 0, stream>>>(
        emissions, lengths, transitions, start_t, end_t, out);
}